// Round 10
// baseline (2531.064 us; speedup 1.0000x reference)
//
#include <hip/hip_runtime.h>
#include <math.h>

#define BATCH 8
#define TPH   512
#define TMEL  4096
#define HCH   256
#define WLEN  256
#define KKTOT 1280
#define PSZ   (TMEL * HCH)   // one split-K partial, in doubles

// ws offsets (in doubles) — high-water 22.087 MB, proven safe R3-R9
#define OFF_WT1 0          // 1280*256
#define OFF_WT2 327680     // 1280*256
#define OFF_H1  655360     // 4096*256
#define OFF_H2  1703936    // 4096*256
#define OFF_M   2752512    // 4096
#define OFF_CEN 2756608    // 4096
#define OFF_GVH 2760704    // 257
// conv split-K partials (8 x 8 MB = 64 MB) live in d_out's outW region
// (67.1 MB), fully consumed by the LN kernels before k_attn overwrites outW.

// ---- wave (64-lane) reduction helpers ----
__device__ __forceinline__ double wsum_d(double v) {
#pragma unroll
    for (int o = 32; o > 0; o >>= 1) v += __shfl_xor(v, o);
    return v;
}
__device__ __forceinline__ float wmax_f(float v) {
#pragma unroll
    for (int o = 32; o > 0; o >>= 1) v = fmaxf(v, __shfl_xor(v, o));
    return v;
}

// fused: blocks 0..2559 transpose weights (O,I,K)->(k*256+i,o) f32->f64;
// block 2560 computes gvh[i] = sum_c gw[c]*projw[c,i], gvh[256] = <gw,projb>
__global__ __launch_bounds__(256) void k_pre(const float* __restrict__ w1,
                                             const float* __restrict__ w2,
                                             double* __restrict__ wt1,
                                             double* __restrict__ wt2,
                                             const float* __restrict__ gw,
                                             const float* __restrict__ projw,
                                             const float* __restrict__ projb,
                                             double* __restrict__ gvh) {
    __shared__ double part[4];
    int idx = blockIdx.x;
    if (idx < 2 * KKTOT) {
        const float* src; double* dst; int kk;
        if (idx < KKTOT) { src = w1; dst = wt1; kk = idx; }
        else             { src = w2; dst = wt2; kk = idx - KKTOT; }
        int k = kk >> 8, i = kk & 255, o = threadIdx.x;
        dst[kk * HCH + o] = (double)src[o * KKTOT + i * 5 + k];
        return;
    }
    int i = threadIdx.x;
    int lane = i & 63, wid = i >> 6;
    double a0 = 0.0, a1 = 0.0, a2 = 0.0, a3 = 0.0;
    for (int c = 0; c < HCH; c += 4) {
        a0 += (double)gw[c + 0] * (double)projw[(c + 0) * HCH + i];
        a1 += (double)gw[c + 1] * (double)projw[(c + 1) * HCH + i];
        a2 += (double)gw[c + 2] * (double)projw[(c + 2) * HCH + i];
        a3 += (double)gw[c + 3] * (double)projw[(c + 3) * HCH + i];
    }
    gvh[i] = ((a0 + a1) + (a2 + a3));
    double s = wsum_d((double)gw[i] * (double)projb[i]);
    if (lane == 0) part[wid] = s;
    __syncthreads();
    if (i == 0) gvh[256] = part[0] + part[1] + part[2] + part[3];
}

// f64 conv-as-GEMM: 64-thread (1-wave) blocks, 64x64 tile, 8x8 micro
// (LDS-BW floor ~51 us/conv at 52 TB/s), single LDS buffer + REGISTER
// PREFETCH (fetch kt+1 overlaps compute kt — hides global latency).
// Split-K x8 -> plain stores to partial z; summed in LN.
template <typename TS>
__global__ __launch_bounds__(64, 2) void k_conv_gemm(const TS* __restrict__ src,
                                                     const float* __restrict__ mask,
                                                     const double* __restrict__ wT,
                                                     double* __restrict__ pout) {
    __shared__ double As[16][78];
    __shared__ double Bs[16][78];
    int t = threadIdx.x;
    int c0 = blockIdx.x * 64;
    int m0 = blockIdx.y * 64;
    int kb0 = blockIdx.z * 160;
    double* out = pout + (size_t)blockIdx.z * PSZ;

    int m = m0 + t;
    int mbase = m & ~511, mt = m & 511;
    int kB = t >> 2, cq = (t & 3) * 16;      // B staging: row kB, cols cq..cq+15
    int scq = cq + 2 * (cq >> 3);            // skewed B store base
    int smt = t + 2 * (t >> 3);              // skewed A store col
    int ay = (t >> 3) * 10;                  // skewed A read base (8 rows)
    int by = (t & 7) * 10;                   // skewed B read base (8 cols)

    double acc[8][8];
#pragma unroll
    for (int i = 0; i < 8; i++)
#pragma unroll
        for (int j = 0; j < 8; j++) acc[i][j] = 0.0;

    double av[16], bv[16];

    auto fetch = [&](int kt) {
        int kb = kb0 + kt * 16;
        int k5 = kb >> 8, ci0 = kb & 255;    // all 16 kk share k5 (16-aligned)
        int tt = mt + k5 - 2;
        if ((unsigned)tt < 512u) {
            int r = mbase + tt;
            double mk = (double)mask[r];
            const TS* sp = src + (size_t)r * HCH + ci0;
#pragma unroll
            for (int k = 0; k < 16; k++) av[k] = (double)sp[k] * mk;
        } else {
#pragma unroll
            for (int k = 0; k < 16; k++) av[k] = 0.0;
        }
        const double* wp = wT + (size_t)(kb + kB) * HCH + c0 + cq;
#pragma unroll
        for (int j = 0; j < 16; j++) bv[j] = wp[j];
    };
    auto store = [&]() {
#pragma unroll
        for (int k = 0; k < 16; k++) As[k][smt] = av[k];
#pragma unroll
        for (int j = 0; j < 16; j++) Bs[kB][scq + j + 2 * (j >> 3)] = bv[j];
    };

    fetch(0);
    store();
    __syncthreads();
    for (int kt = 0; kt < 10; kt++) {
        if (kt + 1 < 10) fetch(kt + 1);      // overlaps compute below
#pragma unroll
        for (int k = 0; k < 16; k++) {
            const double2* Ap = (const double2*)&As[k][ay];
            const double2* Bp = (const double2*)&Bs[k][by];
            double2 A0 = Ap[0], A1 = Ap[1], A2 = Ap[2], A3 = Ap[3];
            double2 B0 = Bp[0], B1 = Bp[1], B2 = Bp[2], B3 = Bp[3];
            double a[8] = {A0.x, A0.y, A1.x, A1.y, A2.x, A2.y, A3.x, A3.y};
            double b[8] = {B0.x, B0.y, B1.x, B1.y, B2.x, B2.y, B3.x, B3.y};
#pragma unroll
            for (int i = 0; i < 8; i++)
#pragma unroll
                for (int j = 0; j < 8; j++) acc[i][j] += a[i] * b[j];
        }
        __syncthreads();
        if (kt + 1 < 10) store();
        __syncthreads();
    }
#pragma unroll
    for (int i = 0; i < 8; i++) {
        double* op = out + (size_t)(m0 + (t >> 3) * 8 + i) * HCH + c0 + (t & 7) * 8;
#pragma unroll
        for (int j = 0; j < 8; j++) op[j] = acc[i][j];
    }
}

// f64: v = sum of 8 split-K partials + bias; channel-LN over 256; relu.
__global__ __launch_bounds__(256) void k_ln_relu(const double* __restrict__ p,
                                                 const float* __restrict__ bias,
                                                 const float* __restrict__ g,
                                                 const float* __restrict__ b,
                                                 double* __restrict__ out) {
    __shared__ double part[4];
    __shared__ double bc;
    int row = blockIdx.x, tid = threadIdx.x;
    int lane = tid & 63, wid = tid >> 6;
    size_t idx = (size_t)row * HCH + tid;
    double v = (double)bias[tid];
#pragma unroll
    for (int z = 0; z < 8; z++) v += p[(size_t)z * PSZ + idx];
    double s = wsum_d(v);
    if (lane == 0) part[wid] = s;
    __syncthreads();
    if (tid == 0) bc = (part[0] + part[1] + part[2] + part[3]) * (1.0 / 256.0);
    __syncthreads();
    double mu = bc;
    double w = v - mu;
    s = wsum_d(w * w);
    if (lane == 0) part[wid] = s;
    __syncthreads();
    if (tid == 0) bc = (part[0] + part[1] + part[2] + part[3]) * (1.0 / 256.0);
    __syncthreads();
    double var = bc;
    double o = w * (1.0 / sqrt(var + 1e-4)) * (double)g[tid] + (double)b[tid];
    out[idx] = fmax(o, 0.0);
}

// ln2 variant: also computes m[row] from in-register h2 (fused k_m2)
__global__ __launch_bounds__(256) void k_ln_relu_m(const double* __restrict__ p,
                                                   const float* __restrict__ bias,
                                                   const float* __restrict__ g,
                                                   const float* __restrict__ b,
                                                   double* __restrict__ out,
                                                   const float* __restrict__ x,
                                                   const float* __restrict__ gw,
                                                   const double* __restrict__ gvh,
                                                   const float* __restrict__ gb,
                                                   const float* __restrict__ mask,
                                                   double* __restrict__ mbuf) {
    __shared__ double part[4];
    __shared__ double bc;
    int row = blockIdx.x, tid = threadIdx.x;
    int lane = tid & 63, wid = tid >> 6;
    size_t idx = (size_t)row * HCH + tid;
    double v = (double)bias[tid];
#pragma unroll
    for (int z = 0; z < 8; z++) v += p[(size_t)z * PSZ + idx];
    double s = wsum_d(v);
    if (lane == 0) part[wid] = s;
    __syncthreads();
    if (tid == 0) bc = (part[0] + part[1] + part[2] + part[3]) * (1.0 / 256.0);
    __syncthreads();
    double mu = bc;
    double w = v - mu;
    s = wsum_d(w * w);
    if (lane == 0) part[wid] = s;
    __syncthreads();
    if (tid == 0) bc = (part[0] + part[1] + part[2] + part[3]) * (1.0 / 256.0);
    __syncthreads();
    double var = bc;
    double o = w * (1.0 / sqrt(var + 1e-4)) * (double)g[tid] + (double)b[tid];
    o = fmax(o, 0.0);
    out[idx] = o;
    double red = gvh[tid] * o + (double)gw[tid] * (double)x[idx];
    s = wsum_d(red);
    if (lane == 0) part[wid] = s;
    __syncthreads();
    if (tid == 0) {
        double acc = part[0] + part[1] + part[2] + part[3];
        double mk = (double)mask[row];
        double g0 = mk * (acc + gvh[256]) + (double)gb[0];
        mbuf[row] = (fmax(g0, 0.0) + 1.0) * mk;
    }
}

// per-batch f64: deterministic dur scatter, mel counts, scale, parallel
// Hillis-Steele inclusive scan -> centers
__global__ __launch_bounds__(512) void k_dur(const double* __restrict__ mbuf,
                                             const int* __restrict__ x2w,
                                             const int* __restrict__ m2w,
                                             double* __restrict__ center,
                                             float* __restrict__ out_mword) {
    __shared__ double ms[512];
    __shared__ int xw[512];
    __shared__ double dur[257];
    __shared__ int cntw[257];
    __shared__ double sa[512], sb[512];
    int b = blockIdx.x, tid = threadIdx.x;
    if (tid < 257) cntw[tid] = 0;
    ms[tid] = mbuf[b * TPH + tid];
    {
        int w = x2w[b * TPH + tid];
        xw[tid] = max(0, min(256, w));
    }
    __syncthreads();
    for (int j = 0; j < TMEL / 512; j++) {
        int ww = m2w[b * TMEL + tid + j * 512];
        ww = max(0, min(256, ww));
        atomicAdd(&cntw[ww], 1);
    }
    __syncthreads();
    if (tid >= 1 && tid <= 256) {
        double s = 0.0;
        for (int t = 0; t < TPH; t++) {
            if (xw[t] == tid) s += ms[t];
        }
        dur[tid] = s;
        out_mword[b * WLEN + tid - 1] = (float)s;
    }
    __syncthreads();
    double msc;
    {
        int w = xw[tid];
        double sc = (double)cntw[w] / (dur[w] + 1e-4);
        msc = ms[tid] + (sc - 1.0) * ms[tid];
    }
    sa[tid] = msc;
    __syncthreads();
    double* cur = sa; double* nxt = sb;
#pragma unroll
    for (int off = 1; off < 512; off <<= 1) {
        double v = cur[tid];
        if (tid >= off) v += cur[tid - off];
        nxt[tid] = v;
        __syncthreads();
        double* tp = cur; cur = nxt; nxt = tp;
    }
    center[b * TPH + tid] = cur[tid] - msc * 0.5;
}

// one WAVE per (b, mel) row, lane-contiguous t = lane*8+j (globally ascending):
// vectorized loads (double2/int4/float4), f64 logits, f32 cast at softmax input,
// shuffle-only reductions, coalesced float4 weight stores, ballot sparse attn.
__global__ __launch_bounds__(256) void k_attn(const float* __restrict__ x,
                                              const double* __restrict__ center,
                                              const int* __restrict__ x2w,
                                              const int* __restrict__ m2w,
                                              const float* __restrict__ mask,
                                              float* __restrict__ outA,
                                              float* __restrict__ outW) {
    int lane = threadIdx.x & 63, wid = threadIdx.x >> 6;
    int r = blockIdx.x * 4 + wid;              // r = b*4096 + mm
    int b = r >> 12;
    const double* cen = center + b * TPH + lane * 8;
    const int* xw = x2w + b * TPH + lane * 8;
    const float* mk = mask + b * TPH + lane * 8;
    int wv = m2w[r];
    double ym = (wv > 0) ? 1.0 : 0.0;
    double posd = (double)(r & 4095);

    double cl[8]; int xl[8]; float ml[8];
#pragma unroll
    for (int q = 0; q < 4; q++) {
        double2 cv = ((const double2*)cen)[q];
        cl[2 * q] = cv.x; cl[2 * q + 1] = cv.y;
    }
    {
        int4 x0 = ((const int4*)xw)[0], x1 = ((const int4*)xw)[1];
        xl[0] = x0.x; xl[1] = x0.y; xl[2] = x0.z; xl[3] = x0.w;
        xl[4] = x1.x; xl[5] = x1.y; xl[6] = x1.z; xl[7] = x1.w;
        float4 m0 = ((const float4*)mk)[0], m1 = ((const float4*)mk)[1];
        ml[0] = m0.x; ml[1] = m0.y; ml[2] = m0.z; ml[3] = m0.w;
        ml[4] = m1.x; ml[5] = m1.y; ml[6] = m1.z; ml[7] = m1.w;
    }

    float ev[8];
    float lmax = -3.0e38f;
#pragma unroll
    for (int j = 0; j < 8; j++) {
        double d = cl[j] - posd;
        double lg = -(d * d) / 10.0;
        double f = ((xl[j] == wv) ? 1.0 : 0.0) * ym * (double)ml[j];
        double masked = lg - (1.0 - f) * 1.0e9;
        float m32 = (float)masked;             // reference's astype(f32)
        ev[j] = m32;
        lmax = fmaxf(lmax, m32);
    }
    lmax = wmax_f(lmax);
    double lsum = 0.0;
#pragma unroll
    for (int j = 0; j < 8; j++) {
        float e = expf(__fsub_rn(ev[j], lmax));
        ev[j] = e;
        lsum += (double)e;
    }
    lsum = wsum_d(lsum);
    float tot = (float)lsum;
    float* wrow = outW + (size_t)r * TPH + lane * 8;
    bool any = false;
#pragma unroll
    for (int j = 0; j < 8; j++) {
        float w = __fdiv_rn(ev[j], tot);
        ev[j] = w;
        any |= (w > 0.f);
    }
    {
        float4 w0 = {ev[0], ev[1], ev[2], ev[3]};
        float4 w1 = {ev[4], ev[5], ev[6], ev[7]};
        ((float4*)wrow)[0] = w0;
        ((float4*)wrow)[1] = w1;
    }
    // sparse attn over ascending t (lane-major = global t order)
    double acc0 = 0.0, acc1 = 0.0, acc2 = 0.0, acc3 = 0.0;
    const float* xb = x + (size_t)b * TPH * HCH;
    unsigned long long mball = __ballot(any);
    while (mball) {
        int l2 = __ffsll(mball) - 1;
        mball &= mball - 1;
#pragma unroll
        for (int j = 0; j < 8; j++) {
            float w = __shfl(ev[j], l2);
            if (w > 0.f) {                     // uniform across lanes
                int t = l2 * 8 + j;
                float4 xv = ((const float4*)(xb + (size_t)t * HCH))[lane];
                acc0 += (double)w * (double)xv.x;
                acc1 += (double)w * (double)xv.y;
                acc2 += (double)w * (double)xv.z;
                acc3 += (double)w * (double)xv.w;
            }
        }
    }
    float4 o;
    o.x = (float)acc0; o.y = (float)acc1; o.z = (float)acc2; o.w = (float)acc3;
    ((float4*)(outA + (size_t)r * HCH))[lane] = o;
}

extern "C" void kernel_launch(void* const* d_in, const int* in_sizes, int n_in,
                              void* d_out, int out_size, void* d_ws, size_t ws_size,
                              hipStream_t stream) {
    (void)in_sizes; (void)n_in; (void)out_size; (void)ws_size;
    const float* x    = (const float*)d_in[0];
    const float* xm   = (const float*)d_in[1];
    const float* pw1  = (const float*)d_in[2];
    const float* pb1  = (const float*)d_in[3];
    const float* g1   = (const float*)d_in[4];
    const float* be1  = (const float*)d_in[5];
    const float* pw2  = (const float*)d_in[6];
    const float* pb2  = (const float*)d_in[7];
    const float* g2   = (const float*)d_in[8];
    const float* be2  = (const float*)d_in[9];
    const float* pjw  = (const float*)d_in[10];
    const float* pjb  = (const float*)d_in[11];
    const float* gw   = (const float*)d_in[12];
    const float* gb   = (const float*)d_in[13];
    const int*   x2w  = (const int*)d_in[14];
    const int*   m2w  = (const int*)d_in[15];

    double* ws   = (double*)d_ws;
    double* wt1  = ws + OFF_WT1;
    double* wt2  = ws + OFF_WT2;
    double* h1   = ws + OFF_H1;
    double* h2   = ws + OFF_H2;
    double* mbuf = ws + OFF_M;
    double* cen  = ws + OFF_CEN;
    double* gvh  = ws + OFF_GVH;

    float* outA = (float*)d_out;
    float* outW = outA + (size_t)BATCH * TMEL * HCH;
    float* outM = outW + (size_t)BATCH * TMEL * TPH;
    // split-K partials: 8 x 8 MB in outW scratch (67.1 MB), consumed by the LN
    // kernels before k_dur/k_attn write outM/outW.
    double* pbuf = (double*)outW;

    hipLaunchKernelGGL(k_pre, dim3(2 * KKTOT + 1), dim3(256), 0, stream,
                       pw1, pw2, wt1, wt2, gw, pjw, pjb, gvh);
    hipLaunchKernelGGL(k_conv_gemm<float>, dim3(4, 64, 8), dim3(64), 0, stream, x, xm, wt1, pbuf);
    hipLaunchKernelGGL(k_ln_relu, dim3(4096), dim3(256), 0, stream, pbuf, pb1, g1, be1, h1);
    hipLaunchKernelGGL(k_conv_gemm<double>, dim3(4, 64, 8), dim3(64), 0, stream, h1, xm, wt2, pbuf);
    hipLaunchKernelGGL(k_ln_relu_m, dim3(4096), dim3(256), 0, stream, pbuf, pb2, g2, be2, h2,
                       x, gw, gvh, gb, xm, mbuf);
    hipLaunchKernelGGL(k_dur, dim3(BATCH), dim3(512), 0, stream, mbuf, x2w, m2w, cen, outM);
    hipLaunchKernelGGL(k_attn, dim3(BATCH * TMEL / 4), dim3(256), 0, stream, x, cen, x2w, m2w, xm, outA, outW);
}

// Round 11
// 397.388 us; speedup vs baseline: 6.3692x; 6.3692x over previous
//
#include <hip/hip_runtime.h>
#include <math.h>

#define BATCH 8
#define TPH   512
#define TMEL  4096
#define HCH   256
#define WLEN  256
#define KKTOT 1280
#define PSZ   (TMEL * HCH)   // one split-K partial, in doubles

// ws offsets (in doubles) — high-water 22.087 MB, proven safe R3-R9
#define OFF_WT1 0          // 1280*256
#define OFF_WT2 327680     // 1280*256
#define OFF_H1  655360     // 4096*256
#define OFF_H2  1703936    // 4096*256
#define OFF_M   2752512    // 4096
#define OFF_CEN 2756608    // 4096
#define OFF_GVH 2760704    // 257
// conv split-K partials (8 x 8 MB = 64 MB) live in d_out's outW region
// (67.1 MB), fully consumed by the LN kernels before k_attn overwrites outW.

// ---- wave (64-lane) reduction helpers ----
__device__ __forceinline__ double wsum_d(double v) {
#pragma unroll
    for (int o = 32; o > 0; o >>= 1) v += __shfl_xor(v, o);
    return v;
}
__device__ __forceinline__ float wmax_f(float v) {
#pragma unroll
    for (int o = 32; o > 0; o >>= 1) v = fmaxf(v, __shfl_xor(v, o));
    return v;
}

// fused: blocks 0..2559 transpose weights (O,I,K)->(k*256+i,o) f32->f64;
// block 2560 computes gvh[i] = sum_c gw[c]*projw[c,i], gvh[256] = <gw,projb>
__global__ __launch_bounds__(256) void k_pre(const float* __restrict__ w1,
                                             const float* __restrict__ w2,
                                             double* __restrict__ wt1,
                                             double* __restrict__ wt2,
                                             const float* __restrict__ gw,
                                             const float* __restrict__ projw,
                                             const float* __restrict__ projb,
                                             double* __restrict__ gvh) {
    __shared__ double part[4];
    int idx = blockIdx.x;
    if (idx < 2 * KKTOT) {
        const float* src; double* dst; int kk;
        if (idx < KKTOT) { src = w1; dst = wt1; kk = idx; }
        else             { src = w2; dst = wt2; kk = idx - KKTOT; }
        int k = kk >> 8, i = kk & 255, o = threadIdx.x;
        dst[kk * HCH + o] = (double)src[o * KKTOT + i * 5 + k];
        return;
    }
    int i = threadIdx.x;
    int lane = i & 63, wid = i >> 6;
    double a0 = 0.0, a1 = 0.0, a2 = 0.0, a3 = 0.0;
    for (int c = 0; c < HCH; c += 4) {
        a0 += (double)gw[c + 0] * (double)projw[(c + 0) * HCH + i];
        a1 += (double)gw[c + 1] * (double)projw[(c + 1) * HCH + i];
        a2 += (double)gw[c + 2] * (double)projw[(c + 2) * HCH + i];
        a3 += (double)gw[c + 3] * (double)projw[(c + 3) * HCH + i];
    }
    gvh[i] = ((a0 + a1) + (a2 + a3));
    double s = wsum_d((double)gw[i] * (double)projb[i]);
    if (lane == 0) part[wid] = s;
    __syncthreads();
    if (i == 0) gvh[256] = part[0] + part[1] + part[2] + part[3];
}

// f64 conv-as-GEMM (R9-proven, 91 us): 64-thread (1-wave) blocks, 64x64 tile,
// 8x8 micro, single LDS buffer, fetch->store->compute per k-tile (NO register
// prefetch: acc[8][8]=128 VGPR leaves no headroom — R10's prefetch spilled to
// scratch, 2.6 GB writes, 12x slowdown). Skewed As/Bs (free 2-way reads).
// Split-K x8 -> plain stores to partial z; summed in LN.
template <typename TS>
__global__ __launch_bounds__(64, 2) void k_conv_gemm(const TS* __restrict__ src,
                                                     const float* __restrict__ mask,
                                                     const double* __restrict__ wT,
                                                     double* __restrict__ pout) {
    __shared__ double As[16][78];
    __shared__ double Bs[16][78];
    int t = threadIdx.x;
    int c0 = blockIdx.x * 64;
    int m0 = blockIdx.y * 64;
    int kb0 = blockIdx.z * 160;
    double* out = pout + (size_t)blockIdx.z * PSZ;

    int m = m0 + t;
    int mbase = m & ~511, mt = m & 511;
    int kB = t >> 2, cq = (t & 3) * 16;      // B staging: row kB, cols cq..cq+15
    int scq = cq + 2 * (cq >> 3);            // skewed B store base
    int smt = t + 2 * (t >> 3);              // skewed A store col
    int ay = (t >> 3) * 10;                  // skewed A read base (8 rows)
    int by = (t & 7) * 10;                   // skewed B read base (8 cols)

    double acc[8][8];
#pragma unroll
    for (int i = 0; i < 8; i++)
#pragma unroll
        for (int j = 0; j < 8; j++) acc[i][j] = 0.0;

    for (int kt = 0; kt < 10; kt++) {
        int kb = kb0 + kt * 16;
        int k5 = kb >> 8, ci0 = kb & 255;    // all 16 kk share k5 (16-aligned)
        double av[16], bv[16];
        int tt = mt + k5 - 2;
        if ((unsigned)tt < 512u) {
            int r = mbase + tt;
            double mk = (double)mask[r];
            const TS* sp = src + (size_t)r * HCH + ci0;
#pragma unroll
            for (int k = 0; k < 16; k++) av[k] = (double)sp[k] * mk;
        } else {
#pragma unroll
            for (int k = 0; k < 16; k++) av[k] = 0.0;
        }
        {
            const double* wp = wT + (size_t)(kb + kB) * HCH + c0 + cq;
#pragma unroll
            for (int j = 0; j < 16; j++) bv[j] = wp[j];
        }
        __syncthreads();
#pragma unroll
        for (int k = 0; k < 16; k++) As[k][smt] = av[k];
#pragma unroll
        for (int j = 0; j < 16; j++) Bs[kB][scq + j + 2 * (j >> 3)] = bv[j];
        __syncthreads();
#pragma unroll
        for (int k = 0; k < 16; k++) {
            const double2* Ap = (const double2*)&As[k][ay];
            const double2* Bp = (const double2*)&Bs[k][by];
            double2 A0 = Ap[0], A1 = Ap[1], A2 = Ap[2], A3 = Ap[3];
            double2 B0 = Bp[0], B1 = Bp[1], B2 = Bp[2], B3 = Bp[3];
            double a[8] = {A0.x, A0.y, A1.x, A1.y, A2.x, A2.y, A3.x, A3.y};
            double b[8] = {B0.x, B0.y, B1.x, B1.y, B2.x, B2.y, B3.x, B3.y};
#pragma unroll
            for (int i = 0; i < 8; i++)
#pragma unroll
                for (int j = 0; j < 8; j++) acc[i][j] += a[i] * b[j];
        }
    }
#pragma unroll
    for (int i = 0; i < 8; i++) {
        double* op = out + (size_t)(m0 + (t >> 3) * 8 + i) * HCH + c0 + (t & 7) * 8;
#pragma unroll
        for (int j = 0; j < 8; j++) op[j] = acc[i][j];
    }
}

// f64: v = sum of 8 split-K partials + bias (2-chain ILP); channel-LN; relu.
__global__ __launch_bounds__(256) void k_ln_relu(const double* __restrict__ p,
                                                 const float* __restrict__ bias,
                                                 const float* __restrict__ g,
                                                 const float* __restrict__ b,
                                                 double* __restrict__ out) {
    __shared__ double part[4];
    __shared__ double bc;
    int row = blockIdx.x, tid = threadIdx.x;
    int lane = tid & 63, wid = tid >> 6;
    size_t idx = (size_t)row * HCH + tid;
    double va = (double)bias[tid], vb = 0.0;
#pragma unroll
    for (int z = 0; z < 8; z += 2) {
        va += p[(size_t)z * PSZ + idx];
        vb += p[(size_t)(z + 1) * PSZ + idx];
    }
    double v = va + vb;
    double s = wsum_d(v);
    if (lane == 0) part[wid] = s;
    __syncthreads();
    if (tid == 0) bc = (part[0] + part[1] + part[2] + part[3]) * (1.0 / 256.0);
    __syncthreads();
    double mu = bc;
    double w = v - mu;
    s = wsum_d(w * w);
    if (lane == 0) part[wid] = s;
    __syncthreads();
    if (tid == 0) bc = (part[0] + part[1] + part[2] + part[3]) * (1.0 / 256.0);
    __syncthreads();
    double var = bc;
    double o = w * (1.0 / sqrt(var + 1e-4)) * (double)g[tid] + (double)b[tid];
    out[idx] = fmax(o, 0.0);
}

// ln2 variant: also computes m[row] from in-register h2 (fused k_m2)
__global__ __launch_bounds__(256) void k_ln_relu_m(const double* __restrict__ p,
                                                   const float* __restrict__ bias,
                                                   const float* __restrict__ g,
                                                   const float* __restrict__ b,
                                                   double* __restrict__ out,
                                                   const float* __restrict__ x,
                                                   const float* __restrict__ gw,
                                                   const double* __restrict__ gvh,
                                                   const float* __restrict__ gb,
                                                   const float* __restrict__ mask,
                                                   double* __restrict__ mbuf) {
    __shared__ double part[4];
    __shared__ double bc;
    int row = blockIdx.x, tid = threadIdx.x;
    int lane = tid & 63, wid = tid >> 6;
    size_t idx = (size_t)row * HCH + tid;
    double va = (double)bias[tid], vb = 0.0;
#pragma unroll
    for (int z = 0; z < 8; z += 2) {
        va += p[(size_t)z * PSZ + idx];
        vb += p[(size_t)(z + 1) * PSZ + idx];
    }
    double v = va + vb;
    double s = wsum_d(v);
    if (lane == 0) part[wid] = s;
    __syncthreads();
    if (tid == 0) bc = (part[0] + part[1] + part[2] + part[3]) * (1.0 / 256.0);
    __syncthreads();
    double mu = bc;
    double w = v - mu;
    s = wsum_d(w * w);
    if (lane == 0) part[wid] = s;
    __syncthreads();
    if (tid == 0) bc = (part[0] + part[1] + part[2] + part[3]) * (1.0 / 256.0);
    __syncthreads();
    double var = bc;
    double o = w * (1.0 / sqrt(var + 1e-4)) * (double)g[tid] + (double)b[tid];
    o = fmax(o, 0.0);
    out[idx] = o;
    double red = gvh[tid] * o + (double)gw[tid] * (double)x[idx];
    s = wsum_d(red);
    if (lane == 0) part[wid] = s;
    __syncthreads();
    if (tid == 0) {
        double acc = part[0] + part[1] + part[2] + part[3];
        double mk = (double)mask[row];
        double g0 = mk * (acc + gvh[256]) + (double)gb[0];
        mbuf[row] = (fmax(g0, 0.0) + 1.0) * mk;
    }
}

// per-batch f64: deterministic dur scatter, mel counts, scale, parallel
// Hillis-Steele inclusive scan -> centers
__global__ __launch_bounds__(512) void k_dur(const double* __restrict__ mbuf,
                                             const int* __restrict__ x2w,
                                             const int* __restrict__ m2w,
                                             double* __restrict__ center,
                                             float* __restrict__ out_mword) {
    __shared__ double ms[512];
    __shared__ int xw[512];
    __shared__ double dur[257];
    __shared__ int cntw[257];
    __shared__ double sa[512], sb[512];
    int b = blockIdx.x, tid = threadIdx.x;
    if (tid < 257) cntw[tid] = 0;
    ms[tid] = mbuf[b * TPH + tid];
    {
        int w = x2w[b * TPH + tid];
        xw[tid] = max(0, min(256, w));
    }
    __syncthreads();
    for (int j = 0; j < TMEL / 512; j++) {
        int ww = m2w[b * TMEL + tid + j * 512];
        ww = max(0, min(256, ww));
        atomicAdd(&cntw[ww], 1);
    }
    __syncthreads();
    if (tid >= 1 && tid <= 256) {
        double s = 0.0;
        for (int t = 0; t < TPH; t++) {
            if (xw[t] == tid) s += ms[t];
        }
        dur[tid] = s;
        out_mword[b * WLEN + tid - 1] = (float)s;
    }
    __syncthreads();
    double msc;
    {
        int w = xw[tid];
        double sc = (double)cntw[w] / (dur[w] + 1e-4);
        msc = ms[tid] + (sc - 1.0) * ms[tid];
    }
    sa[tid] = msc;
    __syncthreads();
    double* cur = sa; double* nxt = sb;
#pragma unroll
    for (int off = 1; off < 512; off <<= 1) {
        double v = cur[tid];
        if (tid >= off) v += cur[tid - off];
        nxt[tid] = v;
        __syncthreads();
        double* tp = cur; cur = nxt; nxt = tp;
    }
    center[b * TPH + tid] = cur[tid] - msc * 0.5;
}

// one WAVE per (b, mel) row, lane-contiguous t = lane*8+j (globally ascending):
// vectorized loads (double2/int4/float4), f64 logits, f32 cast at softmax input,
// shuffle-only reductions, coalesced float4 weight stores, ballot sparse attn.
__global__ __launch_bounds__(256) void k_attn(const float* __restrict__ x,
                                              const double* __restrict__ center,
                                              const int* __restrict__ x2w,
                                              const int* __restrict__ m2w,
                                              const float* __restrict__ mask,
                                              float* __restrict__ outA,
                                              float* __restrict__ outW) {
    int lane = threadIdx.x & 63, wid = threadIdx.x >> 6;
    int r = blockIdx.x * 4 + wid;              // r = b*4096 + mm
    int b = r >> 12;
    const double* cen = center + b * TPH + lane * 8;
    const int* xw = x2w + b * TPH + lane * 8;
    const float* mk = mask + b * TPH + lane * 8;
    int wv = m2w[r];
    double ym = (wv > 0) ? 1.0 : 0.0;
    double posd = (double)(r & 4095);

    double cl[8]; int xl[8]; float ml[8];
#pragma unroll
    for (int q = 0; q < 4; q++) {
        double2 cv = ((const double2*)cen)[q];
        cl[2 * q] = cv.x; cl[2 * q + 1] = cv.y;
    }
    {
        int4 x0 = ((const int4*)xw)[0], x1 = ((const int4*)xw)[1];
        xl[0] = x0.x; xl[1] = x0.y; xl[2] = x0.z; xl[3] = x0.w;
        xl[4] = x1.x; xl[5] = x1.y; xl[6] = x1.z; xl[7] = x1.w;
        float4 m0 = ((const float4*)mk)[0], m1 = ((const float4*)mk)[1];
        ml[0] = m0.x; ml[1] = m0.y; ml[2] = m0.z; ml[3] = m0.w;
        ml[4] = m1.x; ml[5] = m1.y; ml[6] = m1.z; ml[7] = m1.w;
    }

    float ev[8];
    float lmax = -3.0e38f;
#pragma unroll
    for (int j = 0; j < 8; j++) {
        double d = cl[j] - posd;
        double lg = -(d * d) / 10.0;
        double f = ((xl[j] == wv) ? 1.0 : 0.0) * ym * (double)ml[j];
        double masked = lg - (1.0 - f) * 1.0e9;
        float m32 = (float)masked;             // reference's astype(f32)
        ev[j] = m32;
        lmax = fmaxf(lmax, m32);
    }
    lmax = wmax_f(lmax);
    double lsum = 0.0;
#pragma unroll
    for (int j = 0; j < 8; j++) {
        float e = expf(__fsub_rn(ev[j], lmax));
        ev[j] = e;
        lsum += (double)e;
    }
    lsum = wsum_d(lsum);
    float tot = (float)lsum;
    float* wrow = outW + (size_t)r * TPH + lane * 8;
    bool any = false;
#pragma unroll
    for (int j = 0; j < 8; j++) {
        float w = __fdiv_rn(ev[j], tot);
        ev[j] = w;
        any |= (w > 0.f);
    }
    {
        float4 w0 = {ev[0], ev[1], ev[2], ev[3]};
        float4 w1 = {ev[4], ev[5], ev[6], ev[7]};
        ((float4*)wrow)[0] = w0;
        ((float4*)wrow)[1] = w1;
    }
    // sparse attn over ascending t (lane-major = global t order)
    double acc0 = 0.0, acc1 = 0.0, acc2 = 0.0, acc3 = 0.0;
    const float* xb = x + (size_t)b * TPH * HCH;
    unsigned long long mball = __ballot(any);
    while (mball) {
        int l2 = __ffsll(mball) - 1;
        mball &= mball - 1;
#pragma unroll
        for (int j = 0; j < 8; j++) {
            float w = __shfl(ev[j], l2);
            if (w > 0.f) {                     // uniform across lanes
                int t = l2 * 8 + j;
                float4 xv = ((const float4*)(xb + (size_t)t * HCH))[lane];
                acc0 += (double)w * (double)xv.x;
                acc1 += (double)w * (double)xv.y;
                acc2 += (double)w * (double)xv.z;
                acc3 += (double)w * (double)xv.w;
            }
        }
    }
    float4 o;
    o.x = (float)acc0; o.y = (float)acc1; o.z = (float)acc2; o.w = (float)acc3;
    ((float4*)(outA + (size_t)r * HCH))[lane] = o;
}

extern "C" void kernel_launch(void* const* d_in, const int* in_sizes, int n_in,
                              void* d_out, int out_size, void* d_ws, size_t ws_size,
                              hipStream_t stream) {
    (void)in_sizes; (void)n_in; (void)out_size; (void)ws_size;
    const float* x    = (const float*)d_in[0];
    const float* xm   = (const float*)d_in[1];
    const float* pw1  = (const float*)d_in[2];
    const float* pb1  = (const float*)d_in[3];
    const float* g1   = (const float*)d_in[4];
    const float* be1  = (const float*)d_in[5];
    const float* pw2  = (const float*)d_in[6];
    const float* pb2  = (const float*)d_in[7];
    const float* g2   = (const float*)d_in[8];
    const float* be2  = (const float*)d_in[9];
    const float* pjw  = (const float*)d_in[10];
    const float* pjb  = (const float*)d_in[11];
    const float* gw   = (const float*)d_in[12];
    const float* gb   = (const float*)d_in[13];
    const int*   x2w  = (const int*)d_in[14];
    const int*   m2w  = (const int*)d_in[15];

    double* ws   = (double*)d_ws;
    double* wt1  = ws + OFF_WT1;
    double* wt2  = ws + OFF_WT2;
    double* h1   = ws + OFF_H1;
    double* h2   = ws + OFF_H2;
    double* mbuf = ws + OFF_M;
    double* cen  = ws + OFF_CEN;
    double* gvh  = ws + OFF_GVH;

    float* outA = (float*)d_out;
    float* outW = outA + (size_t)BATCH * TMEL * HCH;
    float* outM = outW + (size_t)BATCH * TMEL * TPH;
    // split-K partials: 8 x 8 MB in outW scratch (67.1 MB), consumed by the LN
    // kernels before k_dur/k_attn write outM/outW.
    double* pbuf = (double*)outW;

    hipLaunchKernelGGL(k_pre, dim3(2 * KKTOT + 1), dim3(256), 0, stream,
                       pw1, pw2, wt1, wt2, gw, pjw, pjb, gvh);
    hipLaunchKernelGGL(k_conv_gemm<float>, dim3(4, 64, 8), dim3(64), 0, stream, x, xm, wt1, pbuf);
    hipLaunchKernelGGL(k_ln_relu, dim3(4096), dim3(256), 0, stream, pbuf, pb1, g1, be1, h1);
    hipLaunchKernelGGL(k_conv_gemm<double>, dim3(4, 64, 8), dim3(64), 0, stream, h1, xm, wt2, pbuf);
    hipLaunchKernelGGL(k_ln_relu_m, dim3(4096), dim3(256), 0, stream, pbuf, pb2, g2, be2, h2,
                       x, gw, gvh, gb, xm, mbuf);
    hipLaunchKernelGGL(k_dur, dim3(BATCH), dim3(512), 0, stream, mbuf, x2w, m2w, cen, outM);
    hipLaunchKernelGGL(k_attn, dim3(BATCH * TMEL / 4), dim3(256), 0, stream, x, cen, x2w, m2w, xm, outA, outW);
}

// Round 12
// 385.964 us; speedup vs baseline: 6.5578x; 1.0296x over previous
//
#include <hip/hip_runtime.h>
#include <math.h>

#define BATCH 8
#define TPH   512
#define TMEL  4096
#define HCH   256
#define WLEN  256
#define KKTOT 1280
#define PSZ   (TMEL * HCH)   // one split-K partial, in doubles

// ws offsets (in doubles) — high-water 22.087 MB, proven safe R3-R11
#define OFF_WT1 0          // 1280*256
#define OFF_WT2 327680     // 1280*256
#define OFF_H1  655360     // 4096*256
#define OFF_H2  1703936    // 4096*256
#define OFF_M   2752512    // 4096
#define OFF_CEN 2756608    // 4096
#define OFF_GVH 2760704    // 257
// conv split-K partials (8 x 8 MB = 64 MB) live in d_out's outW region
// (67.1 MB), fully consumed by the LN kernels before k_attn overwrites outW.

// ---- wave (64-lane) reduction helpers ----
__device__ __forceinline__ double wsum_d(double v) {
#pragma unroll
    for (int o = 32; o > 0; o >>= 1) v += __shfl_xor(v, o);
    return v;
}
__device__ __forceinline__ float wmax_f(float v) {
#pragma unroll
    for (int o = 32; o > 0; o >>= 1) v = fmaxf(v, __shfl_xor(v, o));
    return v;
}

// fused: blocks 0..2559 transpose weights (O,I,K)->(k*256+i,o) f32->f64;
// block 2560 computes gvh[i] = sum_c gw[c]*projw[c,i], gvh[256] = <gw,projb>
__global__ __launch_bounds__(256) void k_pre(const float* __restrict__ w1,
                                             const float* __restrict__ w2,
                                             double* __restrict__ wt1,
                                             double* __restrict__ wt2,
                                             const float* __restrict__ gw,
                                             const float* __restrict__ projw,
                                             const float* __restrict__ projb,
                                             double* __restrict__ gvh) {
    __shared__ double part[4];
    int idx = blockIdx.x;
    if (idx < 2 * KKTOT) {
        const float* src; double* dst; int kk;
        if (idx < KKTOT) { src = w1; dst = wt1; kk = idx; }
        else             { src = w2; dst = wt2; kk = idx - KKTOT; }
        int k = kk >> 8, i = kk & 255, o = threadIdx.x;
        dst[kk * HCH + o] = (double)src[o * KKTOT + i * 5 + k];
        return;
    }
    int i = threadIdx.x;
    int lane = i & 63, wid = i >> 6;
    double a0 = 0.0, a1 = 0.0, a2 = 0.0, a3 = 0.0;
    for (int c = 0; c < HCH; c += 4) {
        a0 += (double)gw[c + 0] * (double)projw[(c + 0) * HCH + i];
        a1 += (double)gw[c + 1] * (double)projw[(c + 1) * HCH + i];
        a2 += (double)gw[c + 2] * (double)projw[(c + 2) * HCH + i];
        a3 += (double)gw[c + 3] * (double)projw[(c + 3) * HCH + i];
    }
    gvh[i] = ((a0 + a1) + (a2 + a3));
    double s = wsum_d((double)gw[i] * (double)projb[i]);
    if (lane == 0) part[wid] = s;
    __syncthreads();
    if (i == 0) gvh[256] = part[0] + part[1] + part[2] + part[3];
}

// f64 conv-as-GEMM (R9-proven, 90 us — FROZEN): 64-thread (1-wave) blocks,
// 64x64 tile, 8x8 micro, single LDS buffer, fetch->store->compute (no register
// prefetch: R10 proved it spills at this pressure). Skewed As/Bs. Split-K x8.
template <typename TS>
__global__ __launch_bounds__(64, 2) void k_conv_gemm(const TS* __restrict__ src,
                                                     const float* __restrict__ mask,
                                                     const double* __restrict__ wT,
                                                     double* __restrict__ pout) {
    __shared__ double As[16][78];
    __shared__ double Bs[16][78];
    int t = threadIdx.x;
    int c0 = blockIdx.x * 64;
    int m0 = blockIdx.y * 64;
    int kb0 = blockIdx.z * 160;
    double* out = pout + (size_t)blockIdx.z * PSZ;

    int m = m0 + t;
    int mbase = m & ~511, mt = m & 511;
    int kB = t >> 2, cq = (t & 3) * 16;      // B staging: row kB, cols cq..cq+15
    int scq = cq + 2 * (cq >> 3);            // skewed B store base
    int smt = t + 2 * (t >> 3);              // skewed A store col
    int ay = (t >> 3) * 10;                  // skewed A read base (8 rows)
    int by = (t & 7) * 10;                   // skewed B read base (8 cols)

    double acc[8][8];
#pragma unroll
    for (int i = 0; i < 8; i++)
#pragma unroll
        for (int j = 0; j < 8; j++) acc[i][j] = 0.0;

    for (int kt = 0; kt < 10; kt++) {
        int kb = kb0 + kt * 16;
        int k5 = kb >> 8, ci0 = kb & 255;    // all 16 kk share k5 (16-aligned)
        double av[16], bv[16];
        int tt = mt + k5 - 2;
        if ((unsigned)tt < 512u) {
            int r = mbase + tt;
            double mk = (double)mask[r];
            const TS* sp = src + (size_t)r * HCH + ci0;
#pragma unroll
            for (int k = 0; k < 16; k++) av[k] = (double)sp[k] * mk;
        } else {
#pragma unroll
            for (int k = 0; k < 16; k++) av[k] = 0.0;
        }
        {
            const double* wp = wT + (size_t)(kb + kB) * HCH + c0 + cq;
#pragma unroll
            for (int j = 0; j < 16; j++) bv[j] = wp[j];
        }
        __syncthreads();
#pragma unroll
        for (int k = 0; k < 16; k++) As[k][smt] = av[k];
#pragma unroll
        for (int j = 0; j < 16; j++) Bs[kB][scq + j + 2 * (j >> 3)] = bv[j];
        __syncthreads();
#pragma unroll
        for (int k = 0; k < 16; k++) {
            const double2* Ap = (const double2*)&As[k][ay];
            const double2* Bp = (const double2*)&Bs[k][by];
            double2 A0 = Ap[0], A1 = Ap[1], A2 = Ap[2], A3 = Ap[3];
            double2 B0 = Bp[0], B1 = Bp[1], B2 = Bp[2], B3 = Bp[3];
            double a[8] = {A0.x, A0.y, A1.x, A1.y, A2.x, A2.y, A3.x, A3.y};
            double b[8] = {B0.x, B0.y, B1.x, B1.y, B2.x, B2.y, B3.x, B3.y};
#pragma unroll
            for (int i = 0; i < 8; i++)
#pragma unroll
                for (int j = 0; j < 8; j++) acc[i][j] += a[i] * b[j];
        }
    }
#pragma unroll
    for (int i = 0; i < 8; i++) {
        double* op = out + (size_t)(m0 + (t >> 3) * 8 + i) * HCH + c0 + (t & 7) * 8;
#pragma unroll
        for (int j = 0; j < 8; j++) op[j] = acc[i][j];
    }
}

// f64 LN: 2 rows/block, 128 thr/row, double2 per thread (2 ch). v = sum of 8
// split-K partials + bias; channel-LN over 256; relu.
__global__ __launch_bounds__(256) void k_ln_relu(const double* __restrict__ p,
                                                 const float* __restrict__ bias,
                                                 const float* __restrict__ g,
                                                 const float* __restrict__ b,
                                                 double* __restrict__ out) {
    __shared__ double part[2][2];
    __shared__ double bc[2];
    int tid = threadIdx.x;
    int rr = tid >> 7;                 // row within block
    int inner = tid & 127;
    int lane = tid & 63, wvr = (tid >> 6) & 1;
    int row = blockIdx.x * 2 + rr;
    int c2 = inner * 2;
    size_t idx = (size_t)row * HCH + c2;
    double2 v;
    {
        float2 bs = ((const float2*)(bias + c2))[0];
        v.x = (double)bs.x; v.y = (double)bs.y;
    }
#pragma unroll
    for (int z = 0; z < 8; z++) {
        double2 pv = ((const double2*)(p + (size_t)z * PSZ + idx))[0];
        v.x += pv.x; v.y += pv.y;
    }
    double s = wsum_d(v.x + v.y);
    if (lane == 0) part[rr][wvr] = s;
    __syncthreads();
    if (inner == 0) bc[rr] = (part[rr][0] + part[rr][1]) * (1.0 / 256.0);
    __syncthreads();
    double mu = bc[rr];
    double w0 = v.x - mu, w1 = v.y - mu;
    s = wsum_d(w0 * w0 + w1 * w1);
    if (lane == 0) part[rr][wvr] = s;
    __syncthreads();
    if (inner == 0) bc[rr] = (part[rr][0] + part[rr][1]) * (1.0 / 256.0);
    __syncthreads();
    double rs = 1.0 / sqrt(bc[rr] + 1e-4);
    float2 gg = ((const float2*)(g + c2))[0];
    float2 bb = ((const float2*)(b + c2))[0];
    double2 o;
    o.x = fmax(w0 * rs * (double)gg.x + (double)bb.x, 0.0);
    o.y = fmax(w1 * rs * (double)gg.y + (double)bb.y, 0.0);
    ((double2*)(out + idx))[0] = o;
}

// ln2 variant: also computes m[row] from in-register h2 (fused k_m2)
__global__ __launch_bounds__(256) void k_ln_relu_m(const double* __restrict__ p,
                                                   const float* __restrict__ bias,
                                                   const float* __restrict__ g,
                                                   const float* __restrict__ b,
                                                   double* __restrict__ out,
                                                   const float* __restrict__ x,
                                                   const float* __restrict__ gw,
                                                   const double* __restrict__ gvh,
                                                   const float* __restrict__ gb,
                                                   const float* __restrict__ mask,
                                                   double* __restrict__ mbuf) {
    __shared__ double part[2][2];
    __shared__ double bc[2];
    int tid = threadIdx.x;
    int rr = tid >> 7;
    int inner = tid & 127;
    int lane = tid & 63, wvr = (tid >> 6) & 1;
    int row = blockIdx.x * 2 + rr;
    int c2 = inner * 2;
    size_t idx = (size_t)row * HCH + c2;
    double2 v;
    {
        float2 bs = ((const float2*)(bias + c2))[0];
        v.x = (double)bs.x; v.y = (double)bs.y;
    }
#pragma unroll
    for (int z = 0; z < 8; z++) {
        double2 pv = ((const double2*)(p + (size_t)z * PSZ + idx))[0];
        v.x += pv.x; v.y += pv.y;
    }
    double s = wsum_d(v.x + v.y);
    if (lane == 0) part[rr][wvr] = s;
    __syncthreads();
    if (inner == 0) bc[rr] = (part[rr][0] + part[rr][1]) * (1.0 / 256.0);
    __syncthreads();
    double mu = bc[rr];
    double w0 = v.x - mu, w1 = v.y - mu;
    s = wsum_d(w0 * w0 + w1 * w1);
    if (lane == 0) part[rr][wvr] = s;
    __syncthreads();
    if (inner == 0) bc[rr] = (part[rr][0] + part[rr][1]) * (1.0 / 256.0);
    __syncthreads();
    double rs = 1.0 / sqrt(bc[rr] + 1e-4);
    float2 gg = ((const float2*)(g + c2))[0];
    float2 bb = ((const float2*)(b + c2))[0];
    double o0 = fmax(w0 * rs * (double)gg.x + (double)bb.x, 0.0);
    double o1 = fmax(w1 * rs * (double)gg.y + (double)bb.y, 0.0);
    double2 o; o.x = o0; o.y = o1;
    ((double2*)(out + idx))[0] = o;
    // fused m-row reduction: <gvh,h2> + <gw,x>
    double2 gv = ((const double2*)(gvh + c2))[0];
    float2 xv = ((const float2*)(x + idx))[0];
    float2 gwv = ((const float2*)(gw + c2))[0];
    double red = gv.x * o0 + gv.y * o1 + (double)gwv.x * (double)xv.x + (double)gwv.y * (double)xv.y;
    s = wsum_d(red);
    if (lane == 0) part[rr][wvr] = s;
    __syncthreads();
    if (inner == 0) {
        double acc = part[rr][0] + part[rr][1];
        double mk = (double)mask[row];
        double g0 = mk * (acc + gvh[256]) + (double)gb[0];
        mbuf[row] = (fmax(g0, 0.0) + 1.0) * mk;
    }
}

// per-batch f64: deterministic dur scatter, mel counts, scale, parallel
// Hillis-Steele inclusive scan -> centers
__global__ __launch_bounds__(512) void k_dur(const double* __restrict__ mbuf,
                                             const int* __restrict__ x2w,
                                             const int* __restrict__ m2w,
                                             double* __restrict__ center,
                                             float* __restrict__ out_mword) {
    __shared__ double ms[512];
    __shared__ int xw[512];
    __shared__ double dur[257];
    __shared__ int cntw[257];
    __shared__ double sa[512], sb[512];
    int b = blockIdx.x, tid = threadIdx.x;
    if (tid < 257) cntw[tid] = 0;
    ms[tid] = mbuf[b * TPH + tid];
    {
        int w = x2w[b * TPH + tid];
        xw[tid] = max(0, min(256, w));
    }
    __syncthreads();
    for (int j = 0; j < TMEL / 512; j++) {
        int ww = m2w[b * TMEL + tid + j * 512];
        ww = max(0, min(256, ww));
        atomicAdd(&cntw[ww], 1);
    }
    __syncthreads();
    if (tid >= 1 && tid <= 256) {
        double s = 0.0;
        for (int t = 0; t < TPH; t++) {
            if (xw[t] == tid) s += ms[t];
        }
        dur[tid] = s;
        out_mword[b * WLEN + tid - 1] = (float)s;
    }
    __syncthreads();
    double msc;
    {
        int w = xw[tid];
        double sc = (double)cntw[w] / (dur[w] + 1e-4);
        msc = ms[tid] + (sc - 1.0) * ms[tid];
    }
    sa[tid] = msc;
    __syncthreads();
    double* cur = sa; double* nxt = sb;
#pragma unroll
    for (int off = 1; off < 512; off <<= 1) {
        double v = cur[tid];
        if (tid >= off) v += cur[tid - off];
        nxt[tid] = v;
        __syncthreads();
        double* tp = cur; cur = nxt; nxt = tp;
    }
    center[b * TPH + tid] = cur[tid] - msc * 0.5;
}

// one WAVE per (b, mel) row, lane-contiguous t = lane*8+j (globally ascending):
// vectorized loads, f64 logits, f32 cast at softmax input, shuffle reductions,
// coalesced float4 weight stores, ballot-driven sparse attn.
__global__ __launch_bounds__(256) void k_attn(const float* __restrict__ x,
                                              const double* __restrict__ center,
                                              const int* __restrict__ x2w,
                                              const int* __restrict__ m2w,
                                              const float* __restrict__ mask,
                                              float* __restrict__ outA,
                                              float* __restrict__ outW) {
    int lane = threadIdx.x & 63, wid = threadIdx.x >> 6;
    int r = blockIdx.x * 4 + wid;              // r = b*4096 + mm
    int b = r >> 12;
    const double* cen = center + b * TPH + lane * 8;
    const int* xw = x2w + b * TPH + lane * 8;
    const float* mk = mask + b * TPH + lane * 8;
    int wv = m2w[r];
    double ym = (wv > 0) ? 1.0 : 0.0;
    double posd = (double)(r & 4095);

    double cl[8]; int xl[8]; float ml[8];
#pragma unroll
    for (int q = 0; q < 4; q++) {
        double2 cv = ((const double2*)cen)[q];
        cl[2 * q] = cv.x; cl[2 * q + 1] = cv.y;
    }
    {
        int4 x0 = ((const int4*)xw)[0], x1 = ((const int4*)xw)[1];
        xl[0] = x0.x; xl[1] = x0.y; xl[2] = x0.z; xl[3] = x0.w;
        xl[4] = x1.x; xl[5] = x1.y; xl[6] = x1.z; xl[7] = x1.w;
        float4 m0 = ((const float4*)mk)[0], m1 = ((const float4*)mk)[1];
        ml[0] = m0.x; ml[1] = m0.y; ml[2] = m0.z; ml[3] = m0.w;
        ml[4] = m1.x; ml[5] = m1.y; ml[6] = m1.z; ml[7] = m1.w;
    }

    float ev[8];
    float lmax = -3.0e38f;
#pragma unroll
    for (int j = 0; j < 8; j++) {
        double d = cl[j] - posd;
        double lg = -(d * d) / 10.0;
        double f = ((xl[j] == wv) ? 1.0 : 0.0) * ym * (double)ml[j];
        double masked = lg - (1.0 - f) * 1.0e9;
        float m32 = (float)masked;             // reference's astype(f32)
        ev[j] = m32;
        lmax = fmaxf(lmax, m32);
    }
    lmax = wmax_f(lmax);
    double lsum = 0.0;
#pragma unroll
    for (int j = 0; j < 8; j++) {
        float e = expf(__fsub_rn(ev[j], lmax));
        ev[j] = e;
        lsum += (double)e;
    }
    lsum = wsum_d(lsum);
    float tot = (float)lsum;
    float* wrow = outW + (size_t)r * TPH + lane * 8;
    bool any = false;
#pragma unroll
    for (int j = 0; j < 8; j++) {
        float w = __fdiv_rn(ev[j], tot);
        ev[j] = w;
        any |= (w > 0.f);
    }
    {
        float4 w0 = {ev[0], ev[1], ev[2], ev[3]};
        float4 w1 = {ev[4], ev[5], ev[6], ev[7]};
        ((float4*)wrow)[0] = w0;
        ((float4*)wrow)[1] = w1;
    }
    double acc0 = 0.0, acc1 = 0.0, acc2 = 0.0, acc3 = 0.0;
    const float* xb = x + (size_t)b * TPH * HCH;
    unsigned long long mball = __ballot(any);
    while (mball) {
        int l2 = __ffsll(mball) - 1;
        mball &= mball - 1;
#pragma unroll
        for (int j = 0; j < 8; j++) {
            float w = __shfl(ev[j], l2);
            if (w > 0.f) {                     // uniform across lanes
                int t = l2 * 8 + j;
                float4 xv = ((const float4*)(xb + (size_t)t * HCH))[lane];
                acc0 += (double)w * (double)xv.x;
                acc1 += (double)w * (double)xv.y;
                acc2 += (double)w * (double)xv.z;
                acc3 += (double)w * (double)xv.w;
            }
        }
    }
    float4 o;
    o.x = (float)acc0; o.y = (float)acc1; o.z = (float)acc2; o.w = (float)acc3;
    ((float4*)(outA + (size_t)r * HCH))[lane] = o;
}

extern "C" void kernel_launch(void* const* d_in, const int* in_sizes, int n_in,
                              void* d_out, int out_size, void* d_ws, size_t ws_size,
                              hipStream_t stream) {
    (void)in_sizes; (void)n_in; (void)out_size; (void)ws_size;
    const float* x    = (const float*)d_in[0];
    const float* xm   = (const float*)d_in[1];
    const float* pw1  = (const float*)d_in[2];
    const float* pb1  = (const float*)d_in[3];
    const float* g1   = (const float*)d_in[4];
    const float* be1  = (const float*)d_in[5];
    const float* pw2  = (const float*)d_in[6];
    const float* pb2  = (const float*)d_in[7];
    const float* g2   = (const float*)d_in[8];
    const float* be2  = (const float*)d_in[9];
    const float* pjw  = (const float*)d_in[10];
    const float* pjb  = (const float*)d_in[11];
    const float* gw   = (const float*)d_in[12];
    const float* gb   = (const float*)d_in[13];
    const int*   x2w  = (const int*)d_in[14];
    const int*   m2w  = (const int*)d_in[15];

    double* ws   = (double*)d_ws;
    double* wt1  = ws + OFF_WT1;
    double* wt2  = ws + OFF_WT2;
    double* h1   = ws + OFF_H1;
    double* h2   = ws + OFF_H2;
    double* mbuf = ws + OFF_M;
    double* cen  = ws + OFF_CEN;
    double* gvh  = ws + OFF_GVH;

    float* outA = (float*)d_out;
    float* outW = outA + (size_t)BATCH * TMEL * HCH;
    float* outM = outW + (size_t)BATCH * TMEL * TPH;
    double* pbuf = (double*)outW;

    hipLaunchKernelGGL(k_pre, dim3(2 * KKTOT + 1), dim3(256), 0, stream,
                       pw1, pw2, wt1, wt2, gw, pjw, pjb, gvh);
    hipLaunchKernelGGL(k_conv_gemm<float>, dim3(4, 64, 8), dim3(64), 0, stream, x, xm, wt1, pbuf);
    hipLaunchKernelGGL(k_ln_relu, dim3(2048), dim3(256), 0, stream, pbuf, pb1, g1, be1, h1);
    hipLaunchKernelGGL(k_conv_gemm<double>, dim3(4, 64, 8), dim3(64), 0, stream, h1, xm, wt2, pbuf);
    hipLaunchKernelGGL(k_ln_relu_m, dim3(2048), dim3(256), 0, stream, pbuf, pb2, g2, be2, h2,
                       x, gw, gvh, gb, xm, mbuf);
    hipLaunchKernelGGL(k_dur, dim3(BATCH), dim3(512), 0, stream, mbuf, x2w, m2w, cen, outM);
    hipLaunchKernelGGL(k_attn, dim3(BATCH * TMEL / 4), dim3(256), 0, stream, x, cen, x2w, m2w, xm, outA, outW);
}

// Round 13
// 385.285 us; speedup vs baseline: 6.5693x; 1.0018x over previous
//
#include <hip/hip_runtime.h>
#include <math.h>

#define BATCH 8
#define TPH   512
#define TMEL  4096
#define HCH   256
#define WLEN  256
#define KKTOT 1280
#define PSZ   (TMEL * HCH)   // one split-K partial, in doubles

// ws offsets (in doubles) — high-water 22.087 MB, proven safe R3-R12
#define OFF_WT1 0          // 1280*256
#define OFF_WT2 327680     // 1280*256
#define OFF_H1  655360     // 4096*256
#define OFF_H2  1703936    // 4096*256
#define OFF_M   2752512    // 4096
#define OFF_CEN 2756608    // 4096
#define OFF_GVH 2760704    // 257
// conv split-K partials (8 x 8 MB = 64 MB) live in d_out's outW region
// (67.1 MB), fully consumed by the LN kernels before k_attn overwrites outW.

// ---- wave (64-lane) reduction helpers ----
__device__ __forceinline__ double wsum_d(double v) {
#pragma unroll
    for (int o = 32; o > 0; o >>= 1) v += __shfl_xor(v, o);
    return v;
}
__device__ __forceinline__ float wmax_f(float v) {
#pragma unroll
    for (int o = 32; o > 0; o >>= 1) v = fmaxf(v, __shfl_xor(v, o));
    return v;
}

// fused: blocks 0..2559 transpose weights (O,I,K)->(k*256+i,o) f32->f64;
// block 2560 computes gvh[i] = sum_c gw[c]*projw[c,i], gvh[256] = <gw,projb>
__global__ __launch_bounds__(256) void k_pre(const float* __restrict__ w1,
                                             const float* __restrict__ w2,
                                             double* __restrict__ wt1,
                                             double* __restrict__ wt2,
                                             const float* __restrict__ gw,
                                             const float* __restrict__ projw,
                                             const float* __restrict__ projb,
                                             double* __restrict__ gvh) {
    __shared__ double part[4];
    int idx = blockIdx.x;
    if (idx < 2 * KKTOT) {
        const float* src; double* dst; int kk;
        if (idx < KKTOT) { src = w1; dst = wt1; kk = idx; }
        else             { src = w2; dst = wt2; kk = idx - KKTOT; }
        int k = kk >> 8, i = kk & 255, o = threadIdx.x;
        dst[kk * HCH + o] = (double)src[o * KKTOT + i * 5 + k];
        return;
    }
    int i = threadIdx.x;
    int lane = i & 63, wid = i >> 6;
    double a0 = 0.0, a1 = 0.0, a2 = 0.0, a3 = 0.0;
    for (int c = 0; c < HCH; c += 4) {
        a0 += (double)gw[c + 0] * (double)projw[(c + 0) * HCH + i];
        a1 += (double)gw[c + 1] * (double)projw[(c + 1) * HCH + i];
        a2 += (double)gw[c + 2] * (double)projw[(c + 2) * HCH + i];
        a3 += (double)gw[c + 3] * (double)projw[(c + 3) * HCH + i];
    }
    gvh[i] = ((a0 + a1) + (a2 + a3));
    double s = wsum_d((double)gw[i] * (double)projb[i]);
    if (lane == 0) part[wid] = s;
    __syncthreads();
    if (i == 0) gvh[256] = part[0] + part[1] + part[2] + part[3];
}

// f64 conv-aware GEMM: exploits the 5-tap structure. Split-K by CHANNEL:
// z = 32-ch range, 8 chunks of 4 ci. Per chunk stage raw A rows (64+4 halo,
// 4 ci) and B (5 taps x 4 ci x 64 cols); per ci each thread holds its 12 A
// rows in registers and reuses across all 5 taps: LDS reads 26 b128 / 320 FMA
// (vs 40 for pure GEMM), A global fetch ~5x less. Bank-exact read layout
// (bases r8*20 / cb*20 dwords tile all 32 banks; 8-lane broadcast).
// NOTE: plain launch_bounds(64) — the ",2" variant caps VGPR at 128 and
// spills (R10). Split-K x8 -> plain stores to partial z; summed in LN.
template <typename TS>
__global__ __launch_bounds__(64) void k_conv_gemm(const TS* __restrict__ src,
                                                  const float* __restrict__ mask,
                                                  const double* __restrict__ wT,
                                                  double* __restrict__ pout) {
    __shared__ double As2[4][84];    // [ci][row skewed: pos = r + 2*(r>>3)]
    __shared__ double Bs2[20][78];   // [k5*4+ci][col skewed: pos = c + 2*(c>>3)]
    int t = threadIdx.x;
    int c0 = blockIdx.x * 64;
    int m0 = blockIdx.y * 64;
    int ci_base = blockIdx.z * 32;
    double* out = pout + (size_t)blockIdx.z * PSZ;

    int mb0 = m0 & ~511;            // batch base row
    int mrow0 = m0 & 511;           // tile base within batch
    int r8 = t >> 3, cb = t & 7;
    int aread0 = r8 * 10;           // skewed A read base (rows r8*8..+11)
    int bread0 = cb * 10;           // skewed B read base (cols cb*8..+7)
    int sPos = t + 2 * (t >> 3);    // skewed store position for index t

    double acc[8][8];
#pragma unroll
    for (int i = 0; i < 8; i++)
#pragma unroll
        for (int j = 0; j < 8; j++) acc[i][j] = 0.0;

    for (int ch = 0; ch < 8; ch++) {
        int ci0 = ci_base + ch * 4;
        __syncthreads();            // protect LDS from previous compute reads
        // ---- stage A: rows 0..67 <-> src rows mrow0-2 .. mrow0+65, 4 ci ----
        {
            double v0 = 0.0, v1 = 0.0, v2 = 0.0, v3 = 0.0;
            int rib = mrow0 - 2 + t;
            if ((unsigned)rib < 512u) {
                int r = mb0 + rib;
                double mk = (double)mask[r];
                const TS* sp = src + (size_t)r * HCH + ci0;
                v0 = (double)sp[0] * mk; v1 = (double)sp[1] * mk;
                v2 = (double)sp[2] * mk; v3 = (double)sp[3] * mk;
            }
            As2[0][sPos] = v0; As2[1][sPos] = v1;
            As2[2][sPos] = v2; As2[3][sPos] = v3;
            if (t < 4) {            // halo rows 64..67
                int rowidx = t + 64;
                int rib2 = mrow0 - 2 + rowidx;
                double w0 = 0.0, w1 = 0.0, w2 = 0.0, w3 = 0.0;
                if ((unsigned)rib2 < 512u) {
                    int r = mb0 + rib2;
                    double mk = (double)mask[r];
                    const TS* sp = src + (size_t)r * HCH + ci0;
                    w0 = (double)sp[0] * mk; w1 = (double)sp[1] * mk;
                    w2 = (double)sp[2] * mk; w3 = (double)sp[3] * mk;
                }
                int sA2 = rowidx + 2 * (rowidx >> 3);
                As2[0][sA2] = w0; As2[1][sA2] = w1;
                As2[2][sA2] = w2; As2[3][sA2] = w3;
            }
        }
        // ---- stage B: 20 rows (5 k5 x 4 ci) x 64 cols ----
#pragma unroll
        for (int rr = 0; rr < 20; rr++) {
            int k5 = rr >> 2, cio = rr & 3;
            Bs2[rr][sPos] = wT[(size_t)((k5 << 8) + ci0 + cio) * HCH + c0 + t];
        }
        __syncthreads();
        // ---- compute: per ci, 12 A rows in regs reused across 5 taps ----
#pragma unroll
        for (int ci = 0; ci < 4; ci++) {
            double Ar[12];
            {
                const double2* Ap0 = (const double2*)&As2[ci][aread0];
                double2 a0 = Ap0[0], a1 = Ap0[1], a2 = Ap0[2], a3 = Ap0[3];
                const double2* Ap1 = (const double2*)&As2[ci][aread0 + 10];
                double2 a4 = Ap1[0], a5 = Ap1[1];
                Ar[0] = a0.x; Ar[1] = a0.y; Ar[2] = a1.x; Ar[3] = a1.y;
                Ar[4] = a2.x; Ar[5] = a2.y; Ar[6] = a3.x; Ar[7] = a3.y;
                Ar[8] = a4.x; Ar[9] = a4.y; Ar[10] = a5.x; Ar[11] = a5.y;
            }
#pragma unroll
            for (int k5 = 0; k5 < 5; k5++) {
                const double2* Bp = (const double2*)&Bs2[k5 * 4 + ci][bread0];
                double2 b0 = Bp[0], b1 = Bp[1], b2 = Bp[2], b3 = Bp[3];
                double Br[8] = {b0.x, b0.y, b1.x, b1.y, b2.x, b2.y, b3.x, b3.y};
#pragma unroll
                for (int i = 0; i < 8; i++)
#pragma unroll
                    for (int j = 0; j < 8; j++) acc[i][j] += Ar[i + k5] * Br[j];
            }
        }
    }
#pragma unroll
    for (int i = 0; i < 8; i++) {
        double* op = out + (size_t)(m0 + r8 * 8 + i) * HCH + c0 + cb * 8;
#pragma unroll
        for (int j = 0; j < 8; j++) op[j] = acc[i][j];
    }
}

// f64 LN: 2 rows/block, 128 thr/row, double2 per thread (2 ch). v = sum of 8
// split-K partials + bias; channel-LN over 256; relu.
__global__ __launch_bounds__(256) void k_ln_relu(const double* __restrict__ p,
                                                 const float* __restrict__ bias,
                                                 const float* __restrict__ g,
                                                 const float* __restrict__ b,
                                                 double* __restrict__ out) {
    __shared__ double part[2][2];
    __shared__ double bc[2];
    int tid = threadIdx.x;
    int rr = tid >> 7;                 // row within block
    int inner = tid & 127;
    int lane = tid & 63, wvr = (tid >> 6) & 1;
    int row = blockIdx.x * 2 + rr;
    int c2 = inner * 2;
    size_t idx = (size_t)row * HCH + c2;
    double2 v;
    {
        float2 bs = ((const float2*)(bias + c2))[0];
        v.x = (double)bs.x; v.y = (double)bs.y;
    }
#pragma unroll
    for (int z = 0; z < 8; z++) {
        double2 pv = ((const double2*)(p + (size_t)z * PSZ + idx))[0];
        v.x += pv.x; v.y += pv.y;
    }
    double s = wsum_d(v.x + v.y);
    if (lane == 0) part[rr][wvr] = s;
    __syncthreads();
    if (inner == 0) bc[rr] = (part[rr][0] + part[rr][1]) * (1.0 / 256.0);
    __syncthreads();
    double mu = bc[rr];
    double w0 = v.x - mu, w1 = v.y - mu;
    s = wsum_d(w0 * w0 + w1 * w1);
    if (lane == 0) part[rr][wvr] = s;
    __syncthreads();
    if (inner == 0) bc[rr] = (part[rr][0] + part[rr][1]) * (1.0 / 256.0);
    __syncthreads();
    double rs = 1.0 / sqrt(bc[rr] + 1e-4);
    float2 gg = ((const float2*)(g + c2))[0];
    float2 bb = ((const float2*)(b + c2))[0];
    double2 o;
    o.x = fmax(w0 * rs * (double)gg.x + (double)bb.x, 0.0);
    o.y = fmax(w1 * rs * (double)gg.y + (double)bb.y, 0.0);
    ((double2*)(out + idx))[0] = o;
}

// ln2 variant: also computes m[row] from in-register h2 (fused k_m2)
__global__ __launch_bounds__(256) void k_ln_relu_m(const double* __restrict__ p,
                                                   const float* __restrict__ bias,
                                                   const float* __restrict__ g,
                                                   const float* __restrict__ b,
                                                   double* __restrict__ out,
                                                   const float* __restrict__ x,
                                                   const float* __restrict__ gw,
                                                   const double* __restrict__ gvh,
                                                   const float* __restrict__ gb,
                                                   const float* __restrict__ mask,
                                                   double* __restrict__ mbuf) {
    __shared__ double part[2][2];
    __shared__ double bc[2];
    int tid = threadIdx.x;
    int rr = tid >> 7;
    int inner = tid & 127;
    int lane = tid & 63, wvr = (tid >> 6) & 1;
    int row = blockIdx.x * 2 + rr;
    int c2 = inner * 2;
    size_t idx = (size_t)row * HCH + c2;
    double2 v;
    {
        float2 bs = ((const float2*)(bias + c2))[0];
        v.x = (double)bs.x; v.y = (double)bs.y;
    }
#pragma unroll
    for (int z = 0; z < 8; z++) {
        double2 pv = ((const double2*)(p + (size_t)z * PSZ + idx))[0];
        v.x += pv.x; v.y += pv.y;
    }
    double s = wsum_d(v.x + v.y);
    if (lane == 0) part[rr][wvr] = s;
    __syncthreads();
    if (inner == 0) bc[rr] = (part[rr][0] + part[rr][1]) * (1.0 / 256.0);
    __syncthreads();
    double mu = bc[rr];
    double w0 = v.x - mu, w1 = v.y - mu;
    s = wsum_d(w0 * w0 + w1 * w1);
    if (lane == 0) part[rr][wvr] = s;
    __syncthreads();
    if (inner == 0) bc[rr] = (part[rr][0] + part[rr][1]) * (1.0 / 256.0);
    __syncthreads();
    double rs = 1.0 / sqrt(bc[rr] + 1e-4);
    float2 gg = ((const float2*)(g + c2))[0];
    float2 bb = ((const float2*)(b + c2))[0];
    double o0 = fmax(w0 * rs * (double)gg.x + (double)bb.x, 0.0);
    double o1 = fmax(w1 * rs * (double)gg.y + (double)bb.y, 0.0);
    double2 o; o.x = o0; o.y = o1;
    ((double2*)(out + idx))[0] = o;
    // fused m-row reduction: <gvh,h2> + <gw,x>
    double2 gv = ((const double2*)(gvh + c2))[0];
    float2 xv = ((const float2*)(x + idx))[0];
    float2 gwv = ((const float2*)(gw + c2))[0];
    double red = gv.x * o0 + gv.y * o1 + (double)gwv.x * (double)xv.x + (double)gwv.y * (double)xv.y;
    s = wsum_d(red);
    if (lane == 0) part[rr][wvr] = s;
    __syncthreads();
    if (inner == 0) {
        double acc = part[rr][0] + part[rr][1];
        double mk = (double)mask[row];
        double g0 = mk * (acc + gvh[256]) + (double)gb[0];
        mbuf[row] = (fmax(g0, 0.0) + 1.0) * mk;
    }
}

// per-batch f64: deterministic dur scatter, mel counts, scale, parallel
// Hillis-Steele inclusive scan -> centers
__global__ __launch_bounds__(512) void k_dur(const double* __restrict__ mbuf,
                                             const int* __restrict__ x2w,
                                             const int* __restrict__ m2w,
                                             double* __restrict__ center,
                                             float* __restrict__ out_mword) {
    __shared__ double ms[512];
    __shared__ int xw[512];
    __shared__ double dur[257];
    __shared__ int cntw[257];
    __shared__ double sa[512], sb[512];
    int b = blockIdx.x, tid = threadIdx.x;
    if (tid < 257) cntw[tid] = 0;
    ms[tid] = mbuf[b * TPH + tid];
    {
        int w = x2w[b * TPH + tid];
        xw[tid] = max(0, min(256, w));
    }
    __syncthreads();
    for (int j = 0; j < TMEL / 512; j++) {
        int ww = m2w[b * TMEL + tid + j * 512];
        ww = max(0, min(256, ww));
        atomicAdd(&cntw[ww], 1);
    }
    __syncthreads();
    if (tid >= 1 && tid <= 256) {
        double s = 0.0;
        for (int t = 0; t < TPH; t++) {
            if (xw[t] == tid) s += ms[t];
        }
        dur[tid] = s;
        out_mword[b * WLEN + tid - 1] = (float)s;
    }
    __syncthreads();
    double msc;
    {
        int w = xw[tid];
        double sc = (double)cntw[w] / (dur[w] + 1e-4);
        msc = ms[tid] + (sc - 1.0) * ms[tid];
    }
    sa[tid] = msc;
    __syncthreads();
    double* cur = sa; double* nxt = sb;
#pragma unroll
    for (int off = 1; off < 512; off <<= 1) {
        double v = cur[tid];
        if (tid >= off) v += cur[tid - off];
        nxt[tid] = v;
        __syncthreads();
        double* tp = cur; cur = nxt; nxt = tp;
    }
    center[b * TPH + tid] = cur[tid] - msc * 0.5;
}

// one WAVE per (b, mel) row, lane-contiguous t = lane*8+j (globally ascending):
// vectorized loads, f64 logits, f32 cast at softmax input, shuffle reductions,
// coalesced float4 weight stores, ballot-driven sparse attn.
__global__ __launch_bounds__(256) void k_attn(const float* __restrict__ x,
                                              const double* __restrict__ center,
                                              const int* __restrict__ x2w,
                                              const int* __restrict__ m2w,
                                              const float* __restrict__ mask,
                                              float* __restrict__ outA,
                                              float* __restrict__ outW) {
    int lane = threadIdx.x & 63, wid = threadIdx.x >> 6;
    int r = blockIdx.x * 4 + wid;              // r = b*4096 + mm
    int b = r >> 12;
    const double* cen = center + b * TPH + lane * 8;
    const int* xw = x2w + b * TPH + lane * 8;
    const float* mk = mask + b * TPH + lane * 8;
    int wv = m2w[r];
    double ym = (wv > 0) ? 1.0 : 0.0;
    double posd = (double)(r & 4095);

    double cl[8]; int xl[8]; float ml[8];
#pragma unroll
    for (int q = 0; q < 4; q++) {
        double2 cv = ((const double2*)cen)[q];
        cl[2 * q] = cv.x; cl[2 * q + 1] = cv.y;
    }
    {
        int4 x0 = ((const int4*)xw)[0], x1 = ((const int4*)xw)[1];
        xl[0] = x0.x; xl[1] = x0.y; xl[2] = x0.z; xl[3] = x0.w;
        xl[4] = x1.x; xl[5] = x1.y; xl[6] = x1.z; xl[7] = x1.w;
        float4 m0 = ((const float4*)mk)[0], m1 = ((const float4*)mk)[1];
        ml[0] = m0.x; ml[1] = m0.y; ml[2] = m0.z; ml[3] = m0.w;
        ml[4] = m1.x; ml[5] = m1.y; ml[6] = m1.z; ml[7] = m1.w;
    }

    float ev[8];
    float lmax = -3.0e38f;
#pragma unroll
    for (int j = 0; j < 8; j++) {
        double d = cl[j] - posd;
        double lg = -(d * d) / 10.0;
        double f = ((xl[j] == wv) ? 1.0 : 0.0) * ym * (double)ml[j];
        double masked = lg - (1.0 - f) * 1.0e9;
        float m32 = (float)masked;             // reference's astype(f32)
        ev[j] = m32;
        lmax = fmaxf(lmax, m32);
    }
    lmax = wmax_f(lmax);
    double lsum = 0.0;
#pragma unroll
    for (int j = 0; j < 8; j++) {
        float e = expf(__fsub_rn(ev[j], lmax));
        ev[j] = e;
        lsum += (double)e;
    }
    lsum = wsum_d(lsum);
    float tot = (float)lsum;
    float* wrow = outW + (size_t)r * TPH + lane * 8;
    bool any = false;
#pragma unroll
    for (int j = 0; j < 8; j++) {
        float w = __fdiv_rn(ev[j], tot);
        ev[j] = w;
        any |= (w > 0.f);
    }
    {
        float4 w0 = {ev[0], ev[1], ev[2], ev[3]};
        float4 w1 = {ev[4], ev[5], ev[6], ev[7]};
        ((float4*)wrow)[0] = w0;
        ((float4*)wrow)[1] = w1;
    }
    double acc0 = 0.0, acc1 = 0.0, acc2 = 0.0, acc3 = 0.0;
    const float* xb = x + (size_t)b * TPH * HCH;
    unsigned long long mball = __ballot(any);
    while (mball) {
        int l2 = __ffsll(mball) - 1;
        mball &= mball - 1;
#pragma unroll
        for (int j = 0; j < 8; j++) {
            float w = __shfl(ev[j], l2);
            if (w > 0.f) {                     // uniform across lanes
                int t = l2 * 8 + j;
                float4 xv = ((const float4*)(xb + (size_t)t * HCH))[lane];
                acc0 += (double)w * (double)xv.x;
                acc1 += (double)w * (double)xv.y;
                acc2 += (double)w * (double)xv.z;
                acc3 += (double)w * (double)xv.w;
            }
        }
    }
    float4 o;
    o.x = (float)acc0; o.y = (float)acc1; o.z = (float)acc2; o.w = (float)acc3;
    ((float4*)(outA + (size_t)r * HCH))[lane] = o;
}

extern "C" void kernel_launch(void* const* d_in, const int* in_sizes, int n_in,
                              void* d_out, int out_size, void* d_ws, size_t ws_size,
                              hipStream_t stream) {
    (void)in_sizes; (void)n_in; (void)out_size; (void)ws_size;
    const float* x    = (const float*)d_in[0];
    const float* xm   = (const float*)d_in[1];
    const float* pw1  = (const float*)d_in[2];
    const float* pb1  = (const float*)d_in[3];
    const float* g1   = (const float*)d_in[4];
    const float* be1  = (const float*)d_in[5];
    const float* pw2  = (const float*)d_in[6];
    const float* pb2  = (const float*)d_in[7];
    const float* g2   = (const float*)d_in[8];
    const float* be2  = (const float*)d_in[9];
    const float* pjw  = (const float*)d_in[10];
    const float* pjb  = (const float*)d_in[11];
    const float* gw   = (const float*)d_in[12];
    const float* gb   = (const float*)d_in[13];
    const int*   x2w  = (const int*)d_in[14];
    const int*   m2w  = (const int*)d_in[15];

    double* ws   = (double*)d_ws;
    double* wt1  = ws + OFF_WT1;
    double* wt2  = ws + OFF_WT2;
    double* h1   = ws + OFF_H1;
    double* h2   = ws + OFF_H2;
    double* mbuf = ws + OFF_M;
    double* cen  = ws + OFF_CEN;
    double* gvh  = ws + OFF_GVH;

    float* outA = (float*)d_out;
    float* outW = outA + (size_t)BATCH * TMEL * HCH;
    float* outM = outW + (size_t)BATCH * TMEL * TPH;
    double* pbuf = (double*)outW;

    hipLaunchKernelGGL(k_pre, dim3(2 * KKTOT + 1), dim3(256), 0, stream,
                       pw1, pw2, wt1, wt2, gw, pjw, pjb, gvh);
    hipLaunchKernelGGL(k_conv_gemm<float>, dim3(4, 64, 8), dim3(64), 0, stream, x, xm, wt1, pbuf);
    hipLaunchKernelGGL(k_ln_relu, dim3(2048), dim3(256), 0, stream, pbuf, pb1, g1, be1, h1);
    hipLaunchKernelGGL(k_conv_gemm<double>, dim3(4, 64, 8), dim3(64), 0, stream, h1, xm, wt2, pbuf);
    hipLaunchKernelGGL(k_ln_relu_m, dim3(2048), dim3(256), 0, stream, pbuf, pb2, g2, be2, h2,
                       x, gw, gvh, gb, xm, mbuf);
    hipLaunchKernelGGL(k_dur, dim3(BATCH), dim3(512), 0, stream, mbuf, x2w, m2w, cen, outM);
    hipLaunchKernelGGL(k_attn, dim3(BATCH * TMEL / 4), dim3(256), 0, stream, x, cen, x2w, m2w, xm, outA, outW);
}